// Round 18
// baseline (107.780 us; speedup 1.0000x reference)
//
#include <hip/hip_runtime.h>
#include <hip/hip_bf16.h>

// MultiHeadAttention forward, MI355X gfx950.  B=128,T=256,C=384,H=6,hs=64.
//
// Pipeline (round 18 = round 17 + Q-hoist in attn (catalog m164-m191 arc)):
//   0) convert_inputs: x f32 -> bf16 AND Wq|Wk|Wv -> transposed bf16 (1 launch)
//   2) gemm_qkv     : fused QKV GEMM 32768x1152, 128x128 tile, 512 threads,
//                     dbuf 64KB swizzled LDS, counted vmcnt(4) + raw s_barrier
//                     (2-deep: proven optimal 1/2/3-deep = 53.6/47.7/61.5us);
//                     no setprio (lockstep = T5 null regime, confirmed R17)
//   3) attn_kernel  : 1 block/bh, 8 waves; K+Vt in swizzled LDS; swapped QK^T;
//                     Q fragments HOISTED before staging (in flight under
//                     K/V gl_lds + barrier); setprio kept (independent blocks)
//   4) transpose_w  : Wp -> bf16 [384][384] into q region (q dead)
//   5) proj         : out = o @ Wp + bp (f32), same 8-wave pipelined core
//
// ws usage: exactly 4 * 32768*384 * 2B = 100,663,296 bytes.

#define T_SEQ 256
#define NH 6
#define HS 64
#define CIN 384
#define BATCH 128
#define BT (BATCH * T_SEQ)            // 32768
#define ELEMS ((size_t)BT * CIN)      // 12,582,912 per buffer

using f32x4  = __attribute__((ext_vector_type(4))) float;
using bf16x8 = __attribute__((ext_vector_type(8))) short;  // 8 bf16 in 4 VGPRs

typedef __attribute__((address_space(3))) void       lds_vp;
typedef __attribute__((address_space(1))) const void glob_vp;

// f32 -> bf16 round-to-nearest-even
static __device__ __forceinline__ unsigned short f2bf(float f) {
  union { float f; unsigned u; } v; v.f = f;
  unsigned r = v.u + 0x7FFFu + ((v.u >> 16) & 1u);
  return (unsigned short)(r >> 16);
}

static __device__ __forceinline__ bf16x8 ld_bf8(const unsigned short* p) {
  return *reinterpret_cast<const bf16x8*>(p);
}

static __device__ __forceinline__ void gl_lds16(const void* g, void* l) {
  __builtin_amdgcn_global_load_lds((glob_vp*)g, (lds_vp*)l, 16, 0, 0);
}

// ---------------------------------------------------------------------------
// 0) Fused input conversion.
//    blocks [0, 6144)      : x f32 -> bf16 (8 elems/thread)
//    blocks [6144, 6576)   : Wq|Wk|Wv f32 [384][384] -> bf16 transposed
// ---------------------------------------------------------------------------
__global__ __launch_bounds__(256) void convert_inputs(
    const float* __restrict__ x,
    const float* __restrict__ Wq, const float* __restrict__ Wk,
    const float* __restrict__ Wv,
    unsigned short* __restrict__ xb, unsigned short* __restrict__ wdst)
{
  __shared__ float t[32][33];
  const int bid = blockIdx.x;
  if (bid < 6144) {
    size_t i = (((size_t)bid << 8) + threadIdx.x) << 3;
    float4 f0 = *reinterpret_cast<const float4*>(x + i);
    float4 f1 = *reinterpret_cast<const float4*>(x + i + 4);
    uint4 pk;
    pk.x = f2bf(f0.x) | ((unsigned)f2bf(f0.y) << 16);
    pk.y = f2bf(f0.z) | ((unsigned)f2bf(f0.w) << 16);
    pk.z = f2bf(f1.x) | ((unsigned)f2bf(f1.y) << 16);
    pk.w = f2bf(f1.z) | ((unsigned)f2bf(f1.w) << 16);
    *reinterpret_cast<uint4*>(xb + i) = pk;
  } else {
    int r = bid - 6144;                 // 0..431
    const int z = r / 144; r -= z * 144;
    const int kt = r / 12, nt = r - (r / 12) * 12;
    const float* __restrict__ W = (z == 0) ? Wq : (z == 1) ? Wk : Wv;
    const int tx = threadIdx.x & 31, ty = threadIdx.x >> 5;
    const int k0 = kt * 32, n0 = nt * 32;
#pragma unroll
    for (int i = 0; i < 4; ++i)
      t[ty + 8 * i][tx] = W[(size_t)(k0 + ty + 8 * i) * CIN + n0 + tx];
    __syncthreads();
#pragma unroll
    for (int i = 0; i < 4; ++i)
      wdst[((size_t)z * CIN + n0 + ty + 8 * i) * CIN + k0 + tx] =
          f2bf(t[tx][ty + 8 * i]);
  }
}

// 4) Wp -> bf16 transposed [n][k].  grid(12,12).  Runs AFTER attn.
__global__ __launch_bounds__(256) void transpose_w(
    const float* __restrict__ W, unsigned short* __restrict__ dst)
{
  __shared__ float t[32][33];
  const int tx = threadIdx.x & 31, ty = threadIdx.x >> 5;
  const int k0 = blockIdx.x * 32, n0 = blockIdx.y * 32;
#pragma unroll
  for (int i = 0; i < 4; ++i)
    t[ty + 8 * i][tx] = W[(size_t)(k0 + ty + 8 * i) * CIN + n0 + tx];
  __syncthreads();
#pragma unroll
  for (int i = 0; i < 4; ++i)
    dst[((size_t)(n0 + ty + 8 * i)) * CIN + k0 + tx] = f2bf(t[tx][ty + 8 * i]);
}

// ---------------------------------------------------------------------------
// 2) Fused QKV GEMM, 8 waves (4m x 2n, 32x64 per wave), dbuf + swizzle +
// counted-vmcnt.  Per thread per K-tile: 4 gl_lds (2 A + 2 B); two tiles in
// flight -> steady-state s_waitcnt vmcnt(4).  12 barriers/block.
// Swizzle involution: staged row&7 == l>>3, read row&7 == c&7 -> 0 conflicts.
// ---------------------------------------------------------------------------
__global__ __launch_bounds__(512, 4) void gemm_qkv(
    const unsigned short* __restrict__ xb,
    const unsigned short* __restrict__ wt,
    unsigned short* __restrict__ q_ws, unsigned short* __restrict__ k_ws,
    unsigned short* __restrict__ vT_ws)
{
  __shared__ __align__(16) unsigned short XA[2][128][64];  // 32 KB
  __shared__ __align__(16) unsigned short XB[2][128][64];  // 32 KB

  const int tid = threadIdx.x;
  const int w = tid >> 6, l = tid & 63, g = l >> 4, c = l & 15;
  const int wr = w >> 1, wc = w & 1;   // wr 0..3 (m), wc 0..1 (n)

  const int wid = ((int)blockIdx.x & 7) * 288 + ((int)blockIdx.x >> 3);
  const int n_t = wid % 9, m_t = wid / 9;
  const int m0 = m_t * 128, n0 = n_t * 128;

  f32x4 acc[2][4];
#pragma unroll
  for (int mi = 0; mi < 2; ++mi)
#pragma unroll
    for (int nj = 0; nj < 4; ++nj) { f32x4 zz = {0.f,0.f,0.f,0.f}; acc[mi][nj] = zz; }

  const int lr = l >> 3;               // 0..7
  const int lchk = (l & 7) ^ lr;       // pre-swizzled source chunk
  const char* ga = (const char*)xb +
      ((size_t)(m0 + w * 16 + lr) * CIN + lchk * 8) * 2;
  const char* gb = (const char*)wt +
      ((size_t)(n0 + w * 16 + lr) * CIN + lchk * 8) * 2;

#define STG(buf, t)                                                     \
  {                                                                     \
    _Pragma("unroll")                                                   \
    for (int i_ = 0; i_ < 2; ++i_) {                                    \
      gl_lds16(ga + ((t) * 64 + i_ * 8 * CIN) * 2, &XA[buf][w * 16 + i_ * 8][0]); \
      gl_lds16(gb + ((t) * 64 + i_ * 8 * CIN) * 2, &XB[buf][w * 16 + i_ * 8][0]); \
    }                                                                   \
  }

#define CMP(buf)                                                        \
  {                                                                     \
    _Pragma("unroll")                                                   \
    for (int kk = 0; kk < 2; ++kk) {                                    \
      bf16x8 a[2], b[4];                                                \
      _Pragma("unroll")                                                 \
      for (int mi = 0; mi < 2; ++mi) {                                  \
        const int row = wr * 32 + mi * 16 + c;                          \
        a[mi] = *reinterpret_cast<const bf16x8*>(                       \
            (const char*)&XA[buf][row][0] + (((kk * 4 + g) ^ (c & 7)) << 4)); \
      }                                                                 \
      _Pragma("unroll")                                                 \
      for (int nj = 0; nj < 4; ++nj) {                                  \
        const int row = wc * 64 + nj * 16 + c;                          \
        b[nj] = *reinterpret_cast<const bf16x8*>(                       \
            (const char*)&XB[buf][row][0] + (((kk * 4 + g) ^ (c & 7)) << 4)); \
      }                                                                 \
      _Pragma("unroll")                                                 \
      for (int mi = 0; mi < 2; ++mi)                                    \
        _Pragma("unroll")                                               \
        for (int nj = 0; nj < 4; ++nj)                                  \
          acc[mi][nj] = __builtin_amdgcn_mfma_f32_16x16x32_bf16(        \
              a[mi], b[nj], acc[mi][nj], 0, 0, 0);                      \
    }                                                                   \
  }

  STG(0, 0);
  STG(1, 1);
#pragma unroll 1
  for (int t = 0; t < 5; ++t) {
    asm volatile("s_waitcnt vmcnt(4)" ::: "memory");
    __builtin_amdgcn_s_barrier();
    __builtin_amdgcn_sched_barrier(0);
    const int cur = t & 1;
    CMP(cur);
    __builtin_amdgcn_s_barrier();
    if (t < 4) STG(cur, t + 2);
  }
  asm volatile("s_waitcnt vmcnt(0)" ::: "memory");
  __builtin_amdgcn_s_barrier();
  __builtin_amdgcn_sched_barrier(0);
  CMP(1);
  __syncthreads();   // all waves done with LDS before epilogue reuse

  // Epilogue. Wave's 64 cols = exactly one head (colw 64-aligned).
  const int z = n_t / 3;
  const int colw = (n_t % 3) * 128 + wc * 64;
  const int h = colw >> 6;
  const int b = m0 >> 8;
  const int trow0 = (m0 & 255) + wr * 32;

  if (z == 2) {
    // vT[(bh*64+d)*256 + t], 4 consecutive t -> 8B store
#pragma unroll
    for (int nj = 0; nj < 4; ++nj) {
      const int d = nj * 16 + c;
#pragma unroll
      for (int mi = 0; mi < 2; ++mi) {
        const int t0 = trow0 + mi * 16 + 4 * g;
        ushort4 pk;
        pk.x = f2bf(acc[mi][nj][0]); pk.y = f2bf(acc[mi][nj][1]);
        pk.z = f2bf(acc[mi][nj][2]); pk.w = f2bf(acc[mi][nj][3]);
        *reinterpret_cast<ushort4*>(
            vT_ws + (((size_t)b * NH + h) * HS + d) * T_SEQ + t0) = pk;
      }
    }
  } else {
    // q/k: bounce wave's 32x64 tile through LDS (chunk-swizzled), then
    // conflict-free 16B reads -> coalesced dwordx4 stores.
    unsigned short* dstb = (z == 0) ? q_ws : k_ws;
    char* OS = (char*)XA + w * 4096;   // per-wave 4 KB region (8 x 4KB = 32KB)
#pragma unroll
    for (int nj = 0; nj < 4; ++nj)
#pragma unroll
      for (int mi = 0; mi < 2; ++mi)
#pragma unroll
        for (int i = 0; i < 4; ++i) {
          const int r = mi * 16 + 4 * g + i;           // row in tile (0..31)
          const int chk = (nj * 2 + (c >> 3)) ^ (r & 7);
          *reinterpret_cast<unsigned short*>(
              OS + r * 128 + (chk << 4) + (c & 7) * 2) = f2bf(acc[mi][nj][i]);
        }
    __syncthreads();   // z is block-uniform; orders LDS ops
    unsigned short* gdst = dstb + (((size_t)b * NH + h) * T_SEQ + trow0) * HS;
#pragma unroll
    for (int p = 0; p < 4; ++p) {
      const int r = p * 8 + (l >> 3);                  // 0..31
      const int chk = (l & 7) ^ (r & 7);
      uint4 v = *reinterpret_cast<const uint4*>(OS + r * 128 + (chk << 4));
      *reinterpret_cast<uint4*>((char*)gdst + r * 128 + (l & 7) * 16) = v;
    }
  }
#undef STG
#undef CMP
}

// ---------------------------------------------------------------------------
// 3) attention.  Q fragments now passed in (hoisted in the kernel body so
// the loads fly under K/V staging + barrier).  Otherwise unchanged.
// ---------------------------------------------------------------------------
template<int NT>
__device__ __forceinline__ void attn_tile(
    bf16x8 qb0, bf16x8 qb1,
    const unsigned short* KL, const unsigned short* VL,
    unsigned short* __restrict__ o_ws, int bh, int qt, int g, int c)
{
  const int q0 = qt * 16;
  const int kxor = (c & 7) << 4;

  f32x4 s[NT];
#pragma unroll
  for (int kt = 0; kt < NT; ++kt) {
    const char* krow = (const char*)KL + (kt * 16 + c) * 128;
    bf16x8 ka0 = *reinterpret_cast<const bf16x8*>(krow + ((g * 16) ^ kxor));
    bf16x8 ka1 = *reinterpret_cast<const bf16x8*>(krow + ((64 + g * 16) ^ kxor));
    f32x4 z = {0.f, 0.f, 0.f, 0.f};
    __builtin_amdgcn_s_setprio(1);
    z = __builtin_amdgcn_mfma_f32_16x16x32_bf16(ka0, qb0, z, 0, 0, 0);
    z = __builtin_amdgcn_mfma_f32_16x16x32_bf16(ka1, qb1, z, 0, 0, 0);
    __builtin_amdgcn_s_setprio(0);
    s[kt] = z;
  }

  const float sc = 0.07362372251839260f;  // 384^-0.5 * log2(e)
  float mx = -1e30f;
#pragma unroll
  for (int kt = 0; kt < NT; ++kt)
#pragma unroll
    for (int i = 0; i < 4; ++i) {
      const int k = kt * 16 + 4 * g + i;
      float v = (k <= q0 + c) ? s[kt][i] * sc : -1e30f;
      s[kt][i] = v;
      mx = fmaxf(mx, v);
    }
  mx = fmaxf(mx, __shfl_xor(mx, 16));
  mx = fmaxf(mx, __shfl_xor(mx, 32));

  float sum = 0.f;
#pragma unroll
  for (int kt = 0; kt < NT; ++kt)
#pragma unroll
    for (int i = 0; i < 4; ++i) {
      float p = __builtin_exp2f(s[kt][i] - mx);
      s[kt][i] = p;
      sum += p;
    }
  sum += __shfl_xor(sum, 16);
  sum += __shfl_xor(sum, 32);
  const float inv = 1.0f / sum;

  unsigned pk0[NT], pk1[NT];
#pragma unroll
  for (int kt = 0; kt < NT; ++kt) {
    float2 p01 = {s[kt][0] * inv, s[kt][1] * inv};
    float2 p23 = {s[kt][2] * inv, s[kt][3] * inv};
    __hip_bfloat162 b01 = __float22bfloat162_rn(p01);
    __hip_bfloat162 b23 = __float22bfloat162_rn(p23);
    pk0[kt] = *reinterpret_cast<unsigned*>(&b01);
    pk1[kt] = *reinterpret_cast<unsigned*>(&b23);
  }

  f32x4 acc[4];
#pragma unroll
  for (int nt = 0; nt < 4; ++nt) { f32x4 zz = {0.f,0.f,0.f,0.f}; acc[nt] = zz; }

  const int srcA = ((g & 1) << 5) + c;
  const int srcB = srcA + 16;
  const bool hi = (g >= 2);
#pragma unroll
  for (int ks = 0; ks < NT / 2; ++ks) {
    unsigned a0A = __shfl(pk0[2 * ks],     srcA);
    unsigned a1A = __shfl(pk1[2 * ks],     srcA);
    unsigned a0B = __shfl(pk0[2 * ks],     srcB);
    unsigned a1B = __shfl(pk1[2 * ks],     srcB);
    unsigned b0A = __shfl(pk0[2 * ks + 1], srcA);
    unsigned b1A = __shfl(pk1[2 * ks + 1], srcA);
    unsigned b0B = __shfl(pk0[2 * ks + 1], srcB);
    unsigned b1B = __shfl(pk1[2 * ks + 1], srcB);
    union { unsigned u[4]; bf16x8 v; } pa;
    pa.u[0] = hi ? b0A : a0A;
    pa.u[1] = hi ? b1A : a1A;
    pa.u[2] = hi ? b0B : a0B;
    pa.u[3] = hi ? b1B : a1B;
    __builtin_amdgcn_s_setprio(1);
#pragma unroll
    for (int nt = 0; nt < 4; ++nt) {
      const char* vrow = (const char*)VL + (nt * 16 + c) * 512;
      bf16x8 vb = *reinterpret_cast<const bf16x8*>(
          vrow + ((ks * 64 + g * 16) ^ kxor));
      acc[nt] = __builtin_amdgcn_mfma_f32_16x16x32_bf16(pa.v, vb, acc[nt], 0, 0, 0);
    }
    __builtin_amdgcn_s_setprio(0);
  }

  const int b = bh / NH, h = bh % NH;
  unsigned short* ob = o_ws + ((size_t)(b * T_SEQ + q0)) * CIN + h * HS;
#pragma unroll
  for (int nt = 0; nt < 4; ++nt)
#pragma unroll
    for (int i = 0; i < 4; ++i)
      ob[(size_t)(4 * g + i) * CIN + nt * 16 + c] = f2bf(acc[nt][i]);
}

__global__ __launch_bounds__(512, 4) void attn_kernel(
    const unsigned short* __restrict__ q_ws,
    const unsigned short* __restrict__ k_ws,
    const unsigned short* __restrict__ vT_ws,
    unsigned short* __restrict__ o_ws)
{
  __shared__ __align__(16) unsigned short KL[256 * 64];
  __shared__ __align__(16) unsigned short VL[64 * 256];

  const int tid = threadIdx.x;
  const int w = tid >> 6, l = tid & 63, g = l >> 4, c = l & 15;
  const int bh = blockIdx.x;

  // ---- Q-hoist: issue all 4 Q fragment loads BEFORE staging; they fly
  // under the gl_lds issues and the barrier (m164-m191 arc technique) ----
  const unsigned short* qg = q_ws + (size_t)bh * T_SEQ * HS;
  const int qt0 = w, qt1 = 15 - w;   // this wave's two q-tiles
  const char* qr0 = (const char*)qg + (size_t)(qt0 * 16 + c) * 128;
  const char* qr1 = (const char*)qg + (size_t)(qt1 * 16 + c) * 128;
  const bf16x8 qA0 = *reinterpret_cast<const bf16x8*>(qr0 + g * 16);
  const bf16x8 qA1 = *reinterpret_cast<const bf16x8*>(qr0 + 64 + g * 16);
  const bf16x8 qB0 = *reinterpret_cast<const bf16x8*>(qr1 + g * 16);
  const bf16x8 qB1 = *reinterpret_cast<const bf16x8*>(qr1 + 64 + g * 16);

  const char* kg = (const char*)(k_ws + (size_t)bh * T_SEQ * HS);
  const char* vg = (const char*)(vT_ws + (size_t)bh * HS * T_SEQ);
#pragma unroll
  for (int i = 0; i < 4; ++i) {
    const int cid = i * 512 + w * 64 + l;
    const int rk = cid >> 3, pk_ = cid & 7;
    gl_lds16(kg + rk * 128 + ((pk_ ^ (rk & 7)) << 4),
             (char*)KL + (size_t)(i * 512 + w * 64) * 16);
    const int rv = cid >> 5, pv = cid & 31;
    const int sv = (pv & ~7) | ((pv & 7) ^ (rv & 7));
    gl_lds16(vg + rv * 512 + (sv << 4),
             (char*)VL + (size_t)(i * 512 + w * 64) * 16);
  }
  __syncthreads();

  switch (w) {
    case 0: attn_tile<2>(qA0, qA1, KL, VL, o_ws, bh, 0, g, c);
            attn_tile<16>(qB0, qB1, KL, VL, o_ws, bh, 15, g, c); break;
    case 1: attn_tile<2>(qA0, qA1, KL, VL, o_ws, bh, 1, g, c);
            attn_tile<16>(qB0, qB1, KL, VL, o_ws, bh, 14, g, c); break;
    case 2: attn_tile<4>(qA0, qA1, KL, VL, o_ws, bh, 2, g, c);
            attn_tile<14>(qB0, qB1, KL, VL, o_ws, bh, 13, g, c); break;
    case 3: attn_tile<4>(qA0, qA1, KL, VL, o_ws, bh, 3, g, c);
            attn_tile<14>(qB0, qB1, KL, VL, o_ws, bh, 12, g, c); break;
    case 4: attn_tile<6>(qA0, qA1, KL, VL, o_ws, bh, 4, g, c);
            attn_tile<12>(qB0, qB1, KL, VL, o_ws, bh, 11, g, c); break;
    case 5: attn_tile<6>(qA0, qA1, KL, VL, o_ws, bh, 5, g, c);
            attn_tile<12>(qB0, qB1, KL, VL, o_ws, bh, 10, g, c); break;
    case 6: attn_tile<8>(qA0, qA1, KL, VL, o_ws, bh, 6, g, c);
            attn_tile<10>(qB0, qB1, KL, VL, o_ws, bh, 9, g, c); break;
    case 7: attn_tile<8>(qA0, qA1, KL, VL, o_ws, bh, 7, g, c);
            attn_tile<10>(qB0, qB1, KL, VL, o_ws, bh, 8, g, c); break;
  }
}

// ---------------------------------------------------------------------------
// 5) output projection: 8-wave counted-vmcnt pipelined GEMM, f32 stores.
// No setprio (lockstep regime).
// ---------------------------------------------------------------------------
__global__ __launch_bounds__(512, 4) void proj_kernel(
    const unsigned short* __restrict__ ob,
    const unsigned short* __restrict__ wpt,
    const float* __restrict__ bp,
    float* __restrict__ out)
{
  __shared__ __align__(16) unsigned short XA[2][128][64];
  __shared__ __align__(16) unsigned short XB[2][128][64];

  const int tid = threadIdx.x;
  const int w = tid >> 6, l = tid & 63, g = l >> 4, c = l & 15;
  const int wr = w >> 1, wc = w & 1;

  const int wid = ((int)blockIdx.x & 7) * 96 + ((int)blockIdx.x >> 3);
  const int n_t = wid % 3, m_t = wid / 3;
  const int m0 = m_t * 128, n0 = n_t * 128;

  f32x4 acc[2][4];
#pragma unroll
  for (int mi = 0; mi < 2; ++mi)
#pragma unroll
    for (int nj = 0; nj < 4; ++nj) { f32x4 zz = {0.f,0.f,0.f,0.f}; acc[mi][nj] = zz; }

  const int lr = l >> 3;
  const int lchk = (l & 7) ^ lr;
  const char* ga = (const char*)ob +
      ((size_t)(m0 + w * 16 + lr) * CIN + lchk * 8) * 2;
  const char* gb = (const char*)wpt +
      ((size_t)(n0 + w * 16 + lr) * CIN + lchk * 8) * 2;

#define STG(buf, t)                                                     \
  {                                                                     \
    _Pragma("unroll")                                                   \
    for (int i_ = 0; i_ < 2; ++i_) {                                    \
      gl_lds16(ga + ((t) * 64 + i_ * 8 * CIN) * 2, &XA[buf][w * 16 + i_ * 8][0]); \
      gl_lds16(gb + ((t) * 64 + i_ * 8 * CIN) * 2, &XB[buf][w * 16 + i_ * 8][0]); \
    }                                                                   \
  }

#define CMP(buf)                                                        \
  {                                                                     \
    _Pragma("unroll")                                                   \
    for (int kk = 0; kk < 2; ++kk) {                                    \
      bf16x8 a[2], b[4];                                                \
      _Pragma("unroll")                                                 \
      for (int mi = 0; mi < 2; ++mi) {                                  \
        const int row = wr * 32 + mi * 16 + c;                          \
        a[mi] = *reinterpret_cast<const bf16x8*>(                       \
            (const char*)&XA[buf][row][0] + (((kk * 4 + g) ^ (c & 7)) << 4)); \
      }                                                                 \
      _Pragma("unroll")                                                 \
      for (int nj = 0; nj < 4; ++nj) {                                  \
        const int row = wc * 64 + nj * 16 + c;                          \
        b[nj] = *reinterpret_cast<const bf16x8*>(                       \
            (const char*)&XB[buf][row][0] + (((kk * 4 + g) ^ (c & 7)) << 4)); \
      }                                                                 \
      _Pragma("unroll")                                                 \
      for (int mi = 0; mi < 2; ++mi)                                    \
        _Pragma("unroll")                                               \
        for (int nj = 0; nj < 4; ++nj)                                  \
          acc[mi][nj] = __builtin_amdgcn_mfma_f32_16x16x32_bf16(        \
              a[mi], b[nj], acc[mi][nj], 0, 0, 0);                      \
    }                                                                   \
  }

  STG(0, 0);
  STG(1, 1);
#pragma unroll 1
  for (int t = 0; t < 5; ++t) {
    asm volatile("s_waitcnt vmcnt(4)" ::: "memory");
    __builtin_amdgcn_s_barrier();
    __builtin_amdgcn_sched_barrier(0);
    const int cur = t & 1;
    CMP(cur);
    __builtin_amdgcn_s_barrier();
    if (t < 4) STG(cur, t + 2);
  }
  asm volatile("s_waitcnt vmcnt(0)" ::: "memory");
  __builtin_amdgcn_s_barrier();
  __builtin_amdgcn_sched_barrier(0);
  CMP(1);

#pragma unroll
  for (int nj = 0; nj < 4; ++nj) {
    const int col = n0 + wc * 64 + nj * 16 + c;
    const float bias = bp[col];
#pragma unroll
    for (int mi = 0; mi < 2; ++mi) {
      const int mrow = m0 + wr * 32 + mi * 16 + 4 * g;
#pragma unroll
      for (int i = 0; i < 4; ++i)
        out[(size_t)(mrow + i) * CIN + col] = acc[mi][nj][i] + bias;
    }
  }
#undef STG
#undef CMP
}

// ---------------------------------------------------------------------------
extern "C" void kernel_launch(void* const* d_in, const int* in_sizes, int n_in,
                              void* d_out, int out_size, void* d_ws, size_t ws_size,
                              hipStream_t stream)
{
  // setup_inputs order: x, Wk, Wq, Wv, Wp, bp
  const float* x  = (const float*)d_in[0];
  const float* Wk = (const float*)d_in[1];
  const float* Wq = (const float*)d_in[2];
  const float* Wv = (const float*)d_in[3];
  const float* Wp = (const float*)d_in[4];
  const float* bp = (const float*)d_in[5];
  float* out = (float*)d_out;

  unsigned short* ws    = (unsigned short*)d_ws;
  unsigned short* xb_o  = ws;              // x_bf16; aliased as o after qkv
  unsigned short* q_ws  = ws + ELEMS;      // q; aliased as WpT after attn
  unsigned short* k_ws  = ws + 2 * ELEMS;
  unsigned short* vT_ws = ws + 3 * ELEMS;
  unsigned short* wqkvT = (unsigned short*)d_out;  // pre-proj scratch

  convert_inputs<<<6576, 256, 0, stream>>>(x, Wq, Wk, Wv, xb_o, wqkvT);
  gemm_qkv      <<<2304, 512, 0, stream>>>(xb_o, wqkvT, q_ws, k_ws, vT_ws);
  attn_kernel   <<<BATCH * NH, 512, 0, stream>>>(q_ws, k_ws, vT_ws, xb_o);
  transpose_w   <<<dim3(12, 12), 256, 0, stream>>>(Wp, q_ws);
  proj_kernel   <<<768, 512, 0, stream>>>(xb_o, q_ws, bp, out);
}

// Round 19
// 106.775 us; speedup vs baseline: 1.0094x; 1.0094x over previous
//
#include <hip/hip_runtime.h>
#include <hip/hip_bf16.h>

// MultiHeadAttention forward, MI355X gfx950.  B=128,T=256,C=384,H=6,hs=64.
//
// FINAL (round 19 = round 17 restored; session optimum @106.8us, 2.9x from
// round 1's 308.8us).  Configuration is the measured argmin on every axis:
//   - 128x128 tile, BK=64 (beat 64^2, 256x128, BK=32 in direct A/B)
//   - 2-deep counted-vmcnt prefetch (1/2/3-deep = 53.6/47.7/61.5 us)
//   - 512-thread / 8-wave GEMM blocks (occupancy proven non-limiting but free)
//   - XOR-swizzle involution on all LDS tiles (bank conflicts 1.06e7 -> 0)
//   - setprio ONLY in attn (independent blocks); removal from lockstep GEMMs
//     was -1.4us (T5 regime gate confirmed on this workload)
//   - coalesced LDS-bounce q/k epilogue (direct-scatter stores were +4us)
//   - fused input-convert dispatch; swapped-QK^T in-register-softmax attn
//
// Pipeline:
//   0) convert_inputs: x f32 -> bf16 AND Wq|Wk|Wv -> transposed bf16 (1 launch)
//   2) gemm_qkv     : fused QKV GEMM 32768x1152 -> q,k (bf16 [B,H,T,64]),
//                     vT (bf16 [B,H,64,T])
//   3) attn_kernel  : 1 block/bh, 8 waves; K+Vt in swizzled LDS; swapped QK^T
//   4) transpose_w  : Wp -> bf16 [384][384] into q region (q dead)
//   5) proj         : out = o @ Wp + bp (f32)
//
// ws usage: exactly 4 * 32768*384 * 2B = 100,663,296 bytes.

#define T_SEQ 256
#define NH 6
#define HS 64
#define CIN 384
#define BATCH 128
#define BT (BATCH * T_SEQ)            // 32768
#define ELEMS ((size_t)BT * CIN)      // 12,582,912 per buffer

using f32x4  = __attribute__((ext_vector_type(4))) float;
using bf16x8 = __attribute__((ext_vector_type(8))) short;  // 8 bf16 in 4 VGPRs

typedef __attribute__((address_space(3))) void       lds_vp;
typedef __attribute__((address_space(1))) const void glob_vp;

// f32 -> bf16 round-to-nearest-even
static __device__ __forceinline__ unsigned short f2bf(float f) {
  union { float f; unsigned u; } v; v.f = f;
  unsigned r = v.u + 0x7FFFu + ((v.u >> 16) & 1u);
  return (unsigned short)(r >> 16);
}

static __device__ __forceinline__ bf16x8 ld_bf8(const unsigned short* p) {
  return *reinterpret_cast<const bf16x8*>(p);
}

static __device__ __forceinline__ void gl_lds16(const void* g, void* l) {
  __builtin_amdgcn_global_load_lds((glob_vp*)g, (lds_vp*)l, 16, 0, 0);
}

// ---------------------------------------------------------------------------
// 0) Fused input conversion.
//    blocks [0, 6144)      : x f32 -> bf16 (8 elems/thread)
//    blocks [6144, 6576)   : Wq|Wk|Wv f32 [384][384] -> bf16 transposed
// ---------------------------------------------------------------------------
__global__ __launch_bounds__(256) void convert_inputs(
    const float* __restrict__ x,
    const float* __restrict__ Wq, const float* __restrict__ Wk,
    const float* __restrict__ Wv,
    unsigned short* __restrict__ xb, unsigned short* __restrict__ wdst)
{
  __shared__ float t[32][33];
  const int bid = blockIdx.x;
  if (bid < 6144) {
    size_t i = (((size_t)bid << 8) + threadIdx.x) << 3;
    float4 f0 = *reinterpret_cast<const float4*>(x + i);
    float4 f1 = *reinterpret_cast<const float4*>(x + i + 4);
    uint4 pk;
    pk.x = f2bf(f0.x) | ((unsigned)f2bf(f0.y) << 16);
    pk.y = f2bf(f0.z) | ((unsigned)f2bf(f0.w) << 16);
    pk.z = f2bf(f1.x) | ((unsigned)f2bf(f1.y) << 16);
    pk.w = f2bf(f1.z) | ((unsigned)f2bf(f1.w) << 16);
    *reinterpret_cast<uint4*>(xb + i) = pk;
  } else {
    int r = bid - 6144;                 // 0..431
    const int z = r / 144; r -= z * 144;
    const int kt = r / 12, nt = r - (r / 12) * 12;
    const float* __restrict__ W = (z == 0) ? Wq : (z == 1) ? Wk : Wv;
    const int tx = threadIdx.x & 31, ty = threadIdx.x >> 5;
    const int k0 = kt * 32, n0 = nt * 32;
#pragma unroll
    for (int i = 0; i < 4; ++i)
      t[ty + 8 * i][tx] = W[(size_t)(k0 + ty + 8 * i) * CIN + n0 + tx];
    __syncthreads();
#pragma unroll
    for (int i = 0; i < 4; ++i)
      wdst[((size_t)z * CIN + n0 + ty + 8 * i) * CIN + k0 + tx] =
          f2bf(t[tx][ty + 8 * i]);
  }
}

// 4) Wp -> bf16 transposed [n][k].  grid(12,12).  Runs AFTER attn.
__global__ __launch_bounds__(256) void transpose_w(
    const float* __restrict__ W, unsigned short* __restrict__ dst)
{
  __shared__ float t[32][33];
  const int tx = threadIdx.x & 31, ty = threadIdx.x >> 5;
  const int k0 = blockIdx.x * 32, n0 = blockIdx.y * 32;
#pragma unroll
  for (int i = 0; i < 4; ++i)
    t[ty + 8 * i][tx] = W[(size_t)(k0 + ty + 8 * i) * CIN + n0 + tx];
  __syncthreads();
#pragma unroll
  for (int i = 0; i < 4; ++i)
    dst[((size_t)(n0 + ty + 8 * i)) * CIN + k0 + tx] = f2bf(t[tx][ty + 8 * i]);
}

// ---------------------------------------------------------------------------
// 2) Fused QKV GEMM, 8 waves (4m x 2n, 32x64 per wave), dbuf + swizzle +
// counted-vmcnt.  Per thread per K-tile: 4 gl_lds (2 A + 2 B); two tiles in
// flight -> steady-state s_waitcnt vmcnt(4).  12 barriers/block.
// Swizzle involution: staged row&7 == l>>3, read row&7 == c&7 -> 0 conflicts.
// No setprio here: lockstep barrier-synced waves (T5 null regime).
// ---------------------------------------------------------------------------
__global__ __launch_bounds__(512, 4) void gemm_qkv(
    const unsigned short* __restrict__ xb,
    const unsigned short* __restrict__ wt,
    unsigned short* __restrict__ q_ws, unsigned short* __restrict__ k_ws,
    unsigned short* __restrict__ vT_ws)
{
  __shared__ __align__(16) unsigned short XA[2][128][64];  // 32 KB
  __shared__ __align__(16) unsigned short XB[2][128][64];  // 32 KB

  const int tid = threadIdx.x;
  const int w = tid >> 6, l = tid & 63, g = l >> 4, c = l & 15;
  const int wr = w >> 1, wc = w & 1;   // wr 0..3 (m), wc 0..1 (n)

  const int wid = ((int)blockIdx.x & 7) * 288 + ((int)blockIdx.x >> 3);
  const int n_t = wid % 9, m_t = wid / 9;
  const int m0 = m_t * 128, n0 = n_t * 128;

  f32x4 acc[2][4];
#pragma unroll
  for (int mi = 0; mi < 2; ++mi)
#pragma unroll
    for (int nj = 0; nj < 4; ++nj) { f32x4 zz = {0.f,0.f,0.f,0.f}; acc[mi][nj] = zz; }

  const int lr = l >> 3;               // 0..7
  const int lchk = (l & 7) ^ lr;       // pre-swizzled source chunk
  const char* ga = (const char*)xb +
      ((size_t)(m0 + w * 16 + lr) * CIN + lchk * 8) * 2;
  const char* gb = (const char*)wt +
      ((size_t)(n0 + w * 16 + lr) * CIN + lchk * 8) * 2;

#define STG(buf, t)                                                     \
  {                                                                     \
    _Pragma("unroll")                                                   \
    for (int i_ = 0; i_ < 2; ++i_) {                                    \
      gl_lds16(ga + ((t) * 64 + i_ * 8 * CIN) * 2, &XA[buf][w * 16 + i_ * 8][0]); \
      gl_lds16(gb + ((t) * 64 + i_ * 8 * CIN) * 2, &XB[buf][w * 16 + i_ * 8][0]); \
    }                                                                   \
  }

#define CMP(buf)                                                        \
  {                                                                     \
    _Pragma("unroll")                                                   \
    for (int kk = 0; kk < 2; ++kk) {                                    \
      bf16x8 a[2], b[4];                                                \
      _Pragma("unroll")                                                 \
      for (int mi = 0; mi < 2; ++mi) {                                  \
        const int row = wr * 32 + mi * 16 + c;                          \
        a[mi] = *reinterpret_cast<const bf16x8*>(                       \
            (const char*)&XA[buf][row][0] + (((kk * 4 + g) ^ (c & 7)) << 4)); \
      }                                                                 \
      _Pragma("unroll")                                                 \
      for (int nj = 0; nj < 4; ++nj) {                                  \
        const int row = wc * 64 + nj * 16 + c;                          \
        b[nj] = *reinterpret_cast<const bf16x8*>(                       \
            (const char*)&XB[buf][row][0] + (((kk * 4 + g) ^ (c & 7)) << 4)); \
      }                                                                 \
      _Pragma("unroll")                                                 \
      for (int mi = 0; mi < 2; ++mi)                                    \
        _Pragma("unroll")                                               \
        for (int nj = 0; nj < 4; ++nj)                                  \
          acc[mi][nj] = __builtin_amdgcn_mfma_f32_16x16x32_bf16(        \
              a[mi], b[nj], acc[mi][nj], 0, 0, 0);                      \
    }                                                                   \
  }

  STG(0, 0);
  STG(1, 1);
#pragma unroll 1
  for (int t = 0; t < 5; ++t) {
    asm volatile("s_waitcnt vmcnt(4)" ::: "memory");
    __builtin_amdgcn_s_barrier();
    __builtin_amdgcn_sched_barrier(0);
    const int cur = t & 1;
    CMP(cur);
    __builtin_amdgcn_s_barrier();
    if (t < 4) STG(cur, t + 2);
  }
  asm volatile("s_waitcnt vmcnt(0)" ::: "memory");
  __builtin_amdgcn_s_barrier();
  __builtin_amdgcn_sched_barrier(0);
  CMP(1);
  __syncthreads();   // all waves done with LDS before epilogue reuse

  // Epilogue. Wave's 64 cols = exactly one head (colw 64-aligned).
  const int z = n_t / 3;
  const int colw = (n_t % 3) * 128 + wc * 64;
  const int h = colw >> 6;
  const int b = m0 >> 8;
  const int trow0 = (m0 & 255) + wr * 32;

  if (z == 2) {
    // vT[(bh*64+d)*256 + t], 4 consecutive t -> 8B store
#pragma unroll
    for (int nj = 0; nj < 4; ++nj) {
      const int d = nj * 16 + c;
#pragma unroll
      for (int mi = 0; mi < 2; ++mi) {
        const int t0 = trow0 + mi * 16 + 4 * g;
        ushort4 pk;
        pk.x = f2bf(acc[mi][nj][0]); pk.y = f2bf(acc[mi][nj][1]);
        pk.z = f2bf(acc[mi][nj][2]); pk.w = f2bf(acc[mi][nj][3]);
        *reinterpret_cast<ushort4*>(
            vT_ws + (((size_t)b * NH + h) * HS + d) * T_SEQ + t0) = pk;
      }
    }
  } else {
    // q/k: bounce wave's 32x64 tile through LDS (chunk-swizzled), then
    // conflict-free 16B reads -> coalesced dwordx4 stores.
    unsigned short* dstb = (z == 0) ? q_ws : k_ws;
    char* OS = (char*)XA + w * 4096;   // per-wave 4 KB region (8 x 4KB = 32KB)
#pragma unroll
    for (int nj = 0; nj < 4; ++nj)
#pragma unroll
      for (int mi = 0; mi < 2; ++mi)
#pragma unroll
        for (int i = 0; i < 4; ++i) {
          const int r = mi * 16 + 4 * g + i;           // row in tile (0..31)
          const int chk = (nj * 2 + (c >> 3)) ^ (r & 7);
          *reinterpret_cast<unsigned short*>(
              OS + r * 128 + (chk << 4) + (c & 7) * 2) = f2bf(acc[mi][nj][i]);
        }
    __syncthreads();   // z is block-uniform; orders LDS ops
    unsigned short* gdst = dstb + (((size_t)b * NH + h) * T_SEQ + trow0) * HS;
#pragma unroll
    for (int p = 0; p < 4; ++p) {
      const int r = p * 8 + (l >> 3);                  // 0..31
      const int chk = (l & 7) ^ (r & 7);
      uint4 v = *reinterpret_cast<const uint4*>(OS + r * 128 + (chk << 4));
      *reinterpret_cast<uint4*>((char*)gdst + r * 128 + (l & 7) * 16) = v;
    }
  }
#undef STG
#undef CMP
}

// ---------------------------------------------------------------------------
// 3) attention (setprio KEPT: independent blocks = correct T5 regime).
// ---------------------------------------------------------------------------
template<int NT>
__device__ __forceinline__ void attn_tile(
    const unsigned short* __restrict__ qg,
    const unsigned short* KL, const unsigned short* VL,
    unsigned short* __restrict__ o_ws, int bh, int qt, int g, int c)
{
  const int q0 = qt * 16;
  const int kxor = (c & 7) << 4;

  const char* qrow = (const char*)qg + (size_t)(q0 + c) * 128;
  const bf16x8 qb0 = *reinterpret_cast<const bf16x8*>(qrow + g * 16);
  const bf16x8 qb1 = *reinterpret_cast<const bf16x8*>(qrow + 64 + g * 16);

  f32x4 s[NT];
#pragma unroll
  for (int kt = 0; kt < NT; ++kt) {
    const char* krow = (const char*)KL + (kt * 16 + c) * 128;
    bf16x8 ka0 = *reinterpret_cast<const bf16x8*>(krow + ((g * 16) ^ kxor));
    bf16x8 ka1 = *reinterpret_cast<const bf16x8*>(krow + ((64 + g * 16) ^ kxor));
    f32x4 z = {0.f, 0.f, 0.f, 0.f};
    __builtin_amdgcn_s_setprio(1);
    z = __builtin_amdgcn_mfma_f32_16x16x32_bf16(ka0, qb0, z, 0, 0, 0);
    z = __builtin_amdgcn_mfma_f32_16x16x32_bf16(ka1, qb1, z, 0, 0, 0);
    __builtin_amdgcn_s_setprio(0);
    s[kt] = z;
  }

  const float sc = 0.07362372251839260f;  // 384^-0.5 * log2(e)
  float mx = -1e30f;
#pragma unroll
  for (int kt = 0; kt < NT; ++kt)
#pragma unroll
    for (int i = 0; i < 4; ++i) {
      const int k = kt * 16 + 4 * g + i;
      float v = (k <= q0 + c) ? s[kt][i] * sc : -1e30f;
      s[kt][i] = v;
      mx = fmaxf(mx, v);
    }
  mx = fmaxf(mx, __shfl_xor(mx, 16));
  mx = fmaxf(mx, __shfl_xor(mx, 32));

  float sum = 0.f;
#pragma unroll
  for (int kt = 0; kt < NT; ++kt)
#pragma unroll
    for (int i = 0; i < 4; ++i) {
      float p = __builtin_exp2f(s[kt][i] - mx);
      s[kt][i] = p;
      sum += p;
    }
  sum += __shfl_xor(sum, 16);
  sum += __shfl_xor(sum, 32);
  const float inv = 1.0f / sum;

  unsigned pk0[NT], pk1[NT];
#pragma unroll
  for (int kt = 0; kt < NT; ++kt) {
    float2 p01 = {s[kt][0] * inv, s[kt][1] * inv};
    float2 p23 = {s[kt][2] * inv, s[kt][3] * inv};
    __hip_bfloat162 b01 = __float22bfloat162_rn(p01);
    __hip_bfloat162 b23 = __float22bfloat162_rn(p23);
    pk0[kt] = *reinterpret_cast<unsigned*>(&b01);
    pk1[kt] = *reinterpret_cast<unsigned*>(&b23);
  }

  f32x4 acc[4];
#pragma unroll
  for (int nt = 0; nt < 4; ++nt) { f32x4 zz = {0.f,0.f,0.f,0.f}; acc[nt] = zz; }

  const int srcA = ((g & 1) << 5) + c;
  const int srcB = srcA + 16;
  const bool hi = (g >= 2);
#pragma unroll
  for (int ks = 0; ks < NT / 2; ++ks) {
    unsigned a0A = __shfl(pk0[2 * ks],     srcA);
    unsigned a1A = __shfl(pk1[2 * ks],     srcA);
    unsigned a0B = __shfl(pk0[2 * ks],     srcB);
    unsigned a1B = __shfl(pk1[2 * ks],     srcB);
    unsigned b0A = __shfl(pk0[2 * ks + 1], srcA);
    unsigned b1A = __shfl(pk1[2 * ks + 1], srcA);
    unsigned b0B = __shfl(pk0[2 * ks + 1], srcB);
    unsigned b1B = __shfl(pk1[2 * ks + 1], srcB);
    union { unsigned u[4]; bf16x8 v; } pa;
    pa.u[0] = hi ? b0A : a0A;
    pa.u[1] = hi ? b1A : a1A;
    pa.u[2] = hi ? b0B : a0B;
    pa.u[3] = hi ? b1B : a1B;
    __builtin_amdgcn_s_setprio(1);
#pragma unroll
    for (int nt = 0; nt < 4; ++nt) {
      const char* vrow = (const char*)VL + (nt * 16 + c) * 512;
      bf16x8 vb = *reinterpret_cast<const bf16x8*>(
          vrow + ((ks * 64 + g * 16) ^ kxor));
      acc[nt] = __builtin_amdgcn_mfma_f32_16x16x32_bf16(pa.v, vb, acc[nt], 0, 0, 0);
    }
    __builtin_amdgcn_s_setprio(0);
  }

  const int b = bh / NH, h = bh % NH;
  unsigned short* ob = o_ws + ((size_t)(b * T_SEQ + q0)) * CIN + h * HS;
#pragma unroll
  for (int nt = 0; nt < 4; ++nt)
#pragma unroll
    for (int i = 0; i < 4; ++i)
      ob[(size_t)(4 * g + i) * CIN + nt * 16 + c] = f2bf(acc[nt][i]);
}

__global__ __launch_bounds__(512, 4) void attn_kernel(
    const unsigned short* __restrict__ q_ws,
    const unsigned short* __restrict__ k_ws,
    const unsigned short* __restrict__ vT_ws,
    unsigned short* __restrict__ o_ws)
{
  __shared__ __align__(16) unsigned short KL[256 * 64];
  __shared__ __align__(16) unsigned short VL[64 * 256];

  const int tid = threadIdx.x;
  const int w = tid >> 6, l = tid & 63, g = l >> 4, c = l & 15;
  const int bh = blockIdx.x;

  const char* kg = (const char*)(k_ws + (size_t)bh * T_SEQ * HS);
  const char* vg = (const char*)(vT_ws + (size_t)bh * HS * T_SEQ);
#pragma unroll
  for (int i = 0; i < 4; ++i) {
    const int cid = i * 512 + w * 64 + l;
    const int rk = cid >> 3, pk_ = cid & 7;
    gl_lds16(kg + rk * 128 + ((pk_ ^ (rk & 7)) << 4),
             (char*)KL + (size_t)(i * 512 + w * 64) * 16);
    const int rv = cid >> 5, pv = cid & 31;
    const int sv = (pv & ~7) | ((pv & 7) ^ (rv & 7));
    gl_lds16(vg + rv * 512 + (sv << 4),
             (char*)VL + (size_t)(i * 512 + w * 64) * 16);
  }
  __syncthreads();

  const unsigned short* qg = q_ws + (size_t)bh * T_SEQ * HS;
  switch (w) {
    case 0: attn_tile<2>(qg, KL, VL, o_ws, bh, 0, g, c);
            attn_tile<16>(qg, KL, VL, o_ws, bh, 15, g, c); break;
    case 1: attn_tile<2>(qg, KL, VL, o_ws, bh, 1, g, c);
            attn_tile<16>(qg, KL, VL, o_ws, bh, 14, g, c); break;
    case 2: attn_tile<4>(qg, KL, VL, o_ws, bh, 2, g, c);
            attn_tile<14>(qg, KL, VL, o_ws, bh, 13, g, c); break;
    case 3: attn_tile<4>(qg, KL, VL, o_ws, bh, 3, g, c);
            attn_tile<14>(qg, KL, VL, o_ws, bh, 12, g, c); break;
    case 4: attn_tile<6>(qg, KL, VL, o_ws, bh, 4, g, c);
            attn_tile<12>(qg, KL, VL, o_ws, bh, 11, g, c); break;
    case 5: attn_tile<6>(qg, KL, VL, o_ws, bh, 5, g, c);
            attn_tile<12>(qg, KL, VL, o_ws, bh, 10, g, c); break;
    case 6: attn_tile<8>(qg, KL, VL, o_ws, bh, 6, g, c);
            attn_tile<10>(qg, KL, VL, o_ws, bh, 9, g, c); break;
    case 7: attn_tile<8>(qg, KL, VL, o_ws, bh, 7, g, c);
            attn_tile<10>(qg, KL, VL, o_ws, bh, 8, g, c); break;
  }
}

// ---------------------------------------------------------------------------
// 5) output projection: 8-wave counted-vmcnt pipelined GEMM, f32 stores.
// No setprio (lockstep regime).
// ---------------------------------------------------------------------------
__global__ __launch_bounds__(512, 4) void proj_kernel(
    const unsigned short* __restrict__ ob,
    const unsigned short* __restrict__ wpt,
    const float* __restrict__ bp,
    float* __restrict__ out)
{
  __shared__ __align__(16) unsigned short XA[2][128][64];
  __shared__ __align__(16) unsigned short XB[2][128][64];

  const int tid = threadIdx.x;
  const int w = tid >> 6, l = tid & 63, g = l >> 4, c = l & 15;
  const int wr = w >> 1, wc = w & 1;

  const int wid = ((int)blockIdx.x & 7) * 96 + ((int)blockIdx.x >> 3);
  const int n_t = wid % 3, m_t = wid / 3;
  const int m0 = m_t * 128, n0 = n_t * 128;

  f32x4 acc[2][4];
#pragma unroll
  for (int mi = 0; mi < 2; ++mi)
#pragma unroll
    for (int nj = 0; nj < 4; ++nj) { f32x4 zz = {0.f,0.f,0.f,0.f}; acc[mi][nj] = zz; }

  const int lr = l >> 3;
  const int lchk = (l & 7) ^ lr;
  const char* ga = (const char*)ob +
      ((size_t)(m0 + w * 16 + lr) * CIN + lchk * 8) * 2;
  const char* gb = (const char*)wpt +
      ((size_t)(n0 + w * 16 + lr) * CIN + lchk * 8) * 2;

#define STG(buf, t)                                                     \
  {                                                                     \
    _Pragma("unroll")                                                   \
    for (int i_ = 0; i_ < 2; ++i_) {                                    \
      gl_lds16(ga + ((t) * 64 + i_ * 8 * CIN) * 2, &XA[buf][w * 16 + i_ * 8][0]); \
      gl_lds16(gb + ((t) * 64 + i_ * 8 * CIN) * 2, &XB[buf][w * 16 + i_ * 8][0]); \
    }                                                                   \
  }

#define CMP(buf)                                                        \
  {                                                                     \
    _Pragma("unroll")                                                   \
    for (int kk = 0; kk < 2; ++kk) {                                    \
      bf16x8 a[2], b[4];                                                \
      _Pragma("unroll")                                                 \
      for (int mi = 0; mi < 2; ++mi) {                                  \
        const int row = wr * 32 + mi * 16 + c;                          \
        a[mi] = *reinterpret_cast<const bf16x8*>(                       \
            (const char*)&XA[buf][row][0] + (((kk * 4 + g) ^ (c & 7)) << 4)); \
      }                                                                 \
      _Pragma("unroll")                                                 \
      for (int nj = 0; nj < 4; ++nj) {                                  \
        const int row = wc * 64 + nj * 16 + c;                          \
        b[nj] = *reinterpret_cast<const bf16x8*>(                       \
            (const char*)&XB[buf][row][0] + (((kk * 4 + g) ^ (c & 7)) << 4)); \
      }                                                                 \
      _Pragma("unroll")                                                 \
      for (int mi = 0; mi < 2; ++mi)                                    \
        _Pragma("unroll")                                               \
        for (int nj = 0; nj < 4; ++nj)                                  \
          acc[mi][nj] = __builtin_amdgcn_mfma_f32_16x16x32_bf16(        \
              a[mi], b[nj], acc[mi][nj], 0, 0, 0);                      \
    }                                                                   \
  }

  STG(0, 0);
  STG(1, 1);
#pragma unroll 1
  for (int t = 0; t < 5; ++t) {
    asm volatile("s_waitcnt vmcnt(4)" ::: "memory");
    __builtin_amdgcn_s_barrier();
    __builtin_amdgcn_sched_barrier(0);
    const int cur = t & 1;
    CMP(cur);
    __builtin_amdgcn_s_barrier();
    if (t < 4) STG(cur, t + 2);
  }
  asm volatile("s_waitcnt vmcnt(0)" ::: "memory");
  __builtin_amdgcn_s_barrier();
  __builtin_amdgcn_sched_barrier(0);
  CMP(1);

#pragma unroll
  for (int nj = 0; nj < 4; ++nj) {
    const int col = n0 + wc * 64 + nj * 16 + c;
    const float bias = bp[col];
#pragma unroll
    for (int mi = 0; mi < 2; ++mi) {
      const int mrow = m0 + wr * 32 + mi * 16 + 4 * g;
#pragma unroll
      for (int i = 0; i < 4; ++i)
        out[(size_t)(mrow + i) * CIN + col] = acc[mi][nj][i] + bias;
    }
  }
#undef STG
#undef CMP
}

// ---------------------------------------------------------------------------
extern "C" void kernel_launch(void* const* d_in, const int* in_sizes, int n_in,
                              void* d_out, int out_size, void* d_ws, size_t ws_size,
                              hipStream_t stream)
{
  // setup_inputs order: x, Wk, Wq, Wv, Wp, bp
  const float* x  = (const float*)d_in[0];
  const float* Wk = (const float*)d_in[1];
  const float* Wq = (const float*)d_in[2];
  const float* Wv = (const float*)d_in[3];
  const float* Wp = (const float*)d_in[4];
  const float* bp = (const float*)d_in[5];
  float* out = (float*)d_out;

  unsigned short* ws    = (unsigned short*)d_ws;
  unsigned short* xb_o  = ws;              // x_bf16; aliased as o after qkv
  unsigned short* q_ws  = ws + ELEMS;      // q; aliased as WpT after attn
  unsigned short* k_ws  = ws + 2 * ELEMS;
  unsigned short* vT_ws = ws + 3 * ELEMS;
  unsigned short* wqkvT = (unsigned short*)d_out;  // pre-proj scratch

  convert_inputs<<<6576, 256, 0, stream>>>(x, Wq, Wk, Wv, xb_o, wqkvT);
  gemm_qkv      <<<2304, 512, 0, stream>>>(xb_o, wqkvT, q_ws, k_ws, vT_ws);
  attn_kernel   <<<BATCH * NH, 512, 0, stream>>>(q_ws, k_ws, vT_ws, xb_o);
  transpose_w   <<<dim3(12, 12), 256, 0, stream>>>(Wp, q_ws);
  proj_kernel   <<<768, 512, 0, stream>>>(xb_o, q_ws, bp, out);
}